// Round 10
// baseline (13204.279 us; speedup 1.0000x reference)
//
#include <hip/hip_runtime.h>
#include <hip/hip_bf16.h>
#include <stdint.h>

#define TT 512
#define HD 512
#define BB 32
#define MM (BB*TT)     // 16384 rows (b*T+t)
#define NG 3072        // 2 dirs * 3 gates * 512
#define WGD 16         // workgroups per direction
#define CPW 32         // h columns per workgroup

typedef short short8 __attribute__((ext_vector_type(8)));
typedef float f32x4 __attribute__((ext_vector_type(4)));
typedef float f32x2 __attribute__((ext_vector_type(2)));
typedef unsigned short u16;
typedef unsigned int u32;
typedef unsigned long long u64;

__device__ __forceinline__ u16 f2bf(float f) {
  __hip_bfloat16 h = __float2bfloat16(f);
  union { __hip_bfloat16 h; u16 u; } c; c.h = h; return c.u;
}
__device__ __forceinline__ float bf2f(u16 u) {
  union { u32 i; float f; } c; c.i = ((u32)u) << 16; return c.f;
}
__device__ __forceinline__ float sigmf(float x) {
  return 1.0f / (1.0f + __expf(-x));
}
__device__ __forceinline__ float tanhff(float x) {
  float a = __expf(2.0f * x);          // inf -> 1, 0 -> -1 : graceful
  return 1.0f - 2.0f / (a + 1.0f);
}

// ---------------- f32 -> bf16 convert ----------------
__global__ __launch_bounds__(256) void cvt_bf16(const float* __restrict__ in,
                                                u16* __restrict__ out, int n8) {
  int i = blockIdx.x * 256 + threadIdx.x;
  if (i >= n8) return;
  const float4* p = (const float4*)in;
  float4 a = p[2*i], b = p[2*i+1];
  union { short8 v; u16 u[8]; } o;
  o.u[0]=f2bf(a.x); o.u[1]=f2bf(a.y); o.u[2]=f2bf(a.z); o.u[3]=f2bf(a.w);
  o.u[4]=f2bf(b.x); o.u[5]=f2bf(b.y); o.u[6]=f2bf(b.z); o.u[7]=f2bf(b.w);
  ((short8*)out)[i] = o.v;
}

// ---------------- gx GEMM (unchanged) ----------------
__global__ __launch_bounds__(256) void gemm_gx(const u16* __restrict__ A,
                                               const u16* __restrict__ Bw,
                                               char* __restrict__ gxout,
                                               int K, int gxf32) {
  __shared__ __align__(16) u16 lA[128*32];
  __shared__ __align__(16) u16 lB[128*32];
  const int tid = threadIdx.x;
  const int lane = tid & 63;
  const int wid = tid >> 6;
  const int wr = wid >> 1, wc = wid & 1;
  const int bm = blockIdx.y * 128, bn = blockIdx.x * 128;
  const int col = lane & 15, kg = lane >> 4;

  f32x4 acc[4][4];
#pragma unroll
  for (int m = 0; m < 4; ++m)
#pragma unroll
    for (int n = 0; n < 4; ++n) acc[m][n] = (f32x4){0.f,0.f,0.f,0.f};

  const int nkt = K >> 5;
  for (int kt = 0; kt < nkt; ++kt) {
    short8 ra[2], rb[2];
    const int kb = kt * 32;
#pragma unroll
    for (int p = 0; p < 2; ++p) {
      int id = p*256 + tid;
      int row = id >> 2, c = id & 3;
      ra[p] = *(const short8*)(A  + (size_t)(bm+row)*K + kb + c*8);
      rb[p] = *(const short8*)(Bw + (size_t)(bn+row)*K + kb + c*8);
    }
    __syncthreads();
#pragma unroll
    for (int p = 0; p < 2; ++p) {
      int id = p*256 + tid;
      int row = id >> 2, c = id & 3;
      int off = row*64 + ((c ^ ((row>>1)&3))*16);
      *(short8*)((char*)lA + off) = ra[p];
      *(short8*)((char*)lB + off) = rb[p];
    }
    __syncthreads();
    short8 af[4], bf[4];
#pragma unroll
    for (int m = 0; m < 4; ++m) {
      int row = wr*64 + m*16 + col;
      af[m] = *(short8*)((char*)lA + row*64 + ((kg ^ ((row>>1)&3))*16));
    }
#pragma unroll
    for (int n = 0; n < 4; ++n) {
      int row = wc*64 + n*16 + col;
      bf[n] = *(short8*)((char*)lB + row*64 + ((kg ^ ((row>>1)&3))*16));
    }
#pragma unroll
    for (int m = 0; m < 4; ++m)
#pragma unroll
      for (int n = 0; n < 4; ++n)
        acc[m][n] = __builtin_amdgcn_mfma_f32_16x16x32_bf16(af[m], bf[n], acc[m][n], 0,0,0);
  }
#pragma unroll
  for (int m = 0; m < 4; ++m)
#pragma unroll
    for (int n = 0; n < 4; ++n)
#pragma unroll
      for (int r = 0; r < 4; ++r) {
        int rowg = bm + wr*64 + m*16 + kg*4 + r;
        int colg = bn + wc*64 + n*16 + col;
        float v = acc[m][n][r];
        if (gxf32) ((float*)gxout)[(size_t)rowg*NG + colg] = v;
        else       ((u16*)gxout)[(size_t)rowg*NG + colg] = f2bf(v);
      }
}

// ---------------- persistent BiGRU recurrence (direct-to-fragment h reads) ----
// grid = 32 WGs (512 thr, 8 waves): dir = wg>>4, jb = wg&15 -> cols [jb*32,+32).
// MFMA waves (0..5) poll all 16 flags, then bypass-load their A-fragments
// DIRECTLY from the row-major h image in LLC (fragment layout == row-major
// 16B chunks: lane l, kc -> img + (l&15)*1024 + kc*64 + (l>>4)*16). No hstage
// LDS, no swizzle, no barrier B. gx is read straight into registers. One
// barrier per step (C: gh exchange). Publish/drain/flag as R9.
__global__ __launch_bounds__(512, 1) void bigru_rec(const char* __restrict__ gx,
                                                    const u16* __restrict__ whhb,
                                                    const float* __restrict__ b_ih,
                                                    const float* __restrict__ b_hh,
                                                    char* __restrict__ out,
                                                    u16* __restrict__ himg,   // [2][2][32][512]
                                                    u32* __restrict__ flags,  // [2][16] stride 16 dwords
                                                    int gxf32, int outf32) {
  const int wg = blockIdx.x;
  const int dir = wg >> 4;
  const int jb = wg & 15;
  const int tid = threadIdx.x;
  const int lane = tid & 63;
  const int wv = tid >> 6;
  const int col = lane & 15, kg = lane >> 4;

  __shared__ float gh[3][32][33];                  // padded
  __shared__ float bihs[3][32], bhhs[3][32];
  __shared__ u32 lctr;

  // --- one-time: w_hh B-fragments (waves 0..5: gate g=wv>>1, half ch=wv&1) ---
  short8 bfrag[16];
  if (wv < 6) {
    const int g = wv >> 1, ch = wv & 1;
    const u16* wrow = whhb + (size_t)(dir*1536 + g*512 + jb*CPW + ch*16 + col) * 512;
#pragma unroll
    for (int kc = 0; kc < 16; ++kc)
      bfrag[kc] = *(const short8*)(wrow + kc*32 + kg*8);
  }
  if (tid < 96) {
    int g = tid >> 5, j = tid & 31;
    bihs[g][j] = b_ih[dir*1536 + g*512 + jb*CPW + j];
    bhhs[g][j] = b_hh[dir*1536 + g*512 + jb*CPW + j];
  }
  if (tid == 0) lctr = 0;
  __syncthreads();

  const int gb = tid >> 4, gj0 = (tid & 15) * 2;
  float hp0 = 0.f, hp1 = 0.f;

  u32* dirflags = flags + (size_t)dir * WGD * 16;
  u32* myflag = dirflags + (size_t)jb * 16;

  for (int t = 0; t < TT; ++t) {
    const int tt = dir ? (TT - 1 - t) : t;
    const int par = t & 1;

    // --- gx[tt] -> registers (plain loads; immutable data, consumed after C) ---
    f32x2 xrF, xzF, xnF; u32 xrB=0, xzB=0, xnB=0;
    if (gxf32) {
      const float* gp = (const float*)gx + (size_t)(gb*TT+tt)*NG + dir*1536 + jb*CPW + gj0;
      xrF = *(const f32x2*)(gp);
      xzF = *(const f32x2*)(gp + 512);
      xnF = *(const f32x2*)(gp + 1024);
    } else {
      const u16* gp = (const u16*)gx + (size_t)(gb*TT+tt)*NG + dir*1536 + jb*CPW + gj0;
      xrB = *(const u32*)(gp);
      xzB = *(const u32*)(gp + 512);
      xnB = *(const u32*)(gp + 1024);
    }

    // --- MFMA waves: poll all 16 flags, then direct fragment loads + MFMA ---
    if (wv < 6) {
      if (t > 0) {
        const u32 need = (u32)t;
        const u32* fp = dirflags + (size_t)lane * 16;
        int it = 0;
        while (it++ < (1 << 24)) {
          u32 v = (lane < WGD)
                ? __hip_atomic_load(fp, __ATOMIC_RELAXED, __HIP_MEMORY_SCOPE_AGENT)
                : (u32)t;
          if (__all(v >= need)) break;
        }
      }
      __builtin_amdgcn_sched_barrier(0);
      asm volatile("" ::: "memory");   // pin fragment loads AFTER the poll

      const u64* imgq = (const u64*)(himg + ((size_t)dir*2 + par) * 32 * 512);
      // lane fragment qword: (m*16 + col)*128 + kc*8 + kg*2 + h
      u64 fa[16][2][2];
#pragma unroll
      for (int kc = 0; kc < 16; ++kc)
#pragma unroll
        for (int m = 0; m < 2; ++m)
#pragma unroll
          for (int h = 0; h < 2; ++h)
            fa[kc][m][h] = __hip_atomic_load(imgq + (m*16 + col)*128 + kc*8 + kg*2 + h,
                                             __ATOMIC_RELAXED, __HIP_MEMORY_SCOPE_AGENT);

      const int g = wv >> 1, ch = wv & 1;
      f32x4 acc0 = (f32x4){0.f,0.f,0.f,0.f};
      f32x4 acc1 = (f32x4){0.f,0.f,0.f,0.f};
#pragma unroll
      for (int kc = 0; kc < 16; ++kc) {
        union { u64 q[2]; short8 s; } a0, a1;
        a0.q[0] = fa[kc][0][0]; a0.q[1] = fa[kc][0][1];
        a1.q[0] = fa[kc][1][0]; a1.q[1] = fa[kc][1][1];
        acc0 = __builtin_amdgcn_mfma_f32_16x16x32_bf16(a0.s, bfrag[kc], acc0, 0,0,0);
        acc1 = __builtin_amdgcn_mfma_f32_16x16x32_bf16(a1.s, bfrag[kc], acc1, 0,0,0);
      }
#pragma unroll
      for (int r = 0; r < 4; ++r) {
        gh[g][kg*4 + r][ch*16 + col]      = acc0[r];
        gh[g][16 + kg*4 + r][ch*16 + col] = acc1[r];
      }
    }
    __syncthreads();   // (C) gh ready

    // --- gates: thread -> (b=gb, j=gj0, gj0+1) ---
    float hv0, hv1; u32 pv;
    {
      float xr0, xz0, xn0, xr1, xz1, xn1;
      if (gxf32) {
        xr0 = xrF.x; xz0 = xzF.x; xn0 = xnF.x;
        xr1 = xrF.y; xz1 = xzF.y; xn1 = xnF.y;
      } else {
        xr0 = bf2f((u16)(xrB & 0xffff)); xz0 = bf2f((u16)(xzB & 0xffff)); xn0 = bf2f((u16)(xnB & 0xffff));
        xr1 = bf2f((u16)(xrB >> 16));    xz1 = bf2f((u16)(xzB >> 16));    xn1 = bf2f((u16)(xnB >> 16));
      }
      float r0 = sigmf(xr0 + bihs[0][gj0]   + gh[0][gb][gj0]   + bhhs[0][gj0]);
      float z0 = sigmf(xz0 + bihs[1][gj0]   + gh[1][gb][gj0]   + bhhs[1][gj0]);
      float n0 = tanhff(xn0 + bihs[2][gj0]  + r0*(gh[2][gb][gj0] + bhhs[2][gj0]));
      hv0 = (1.f - z0)*n0 + z0*hp0;
      float r1 = sigmf(xr1 + bihs[0][gj0+1] + gh[0][gb][gj0+1] + bhhs[0][gj0+1]);
      float z1 = sigmf(xz1 + bihs[1][gj0+1] + gh[1][gb][gj0+1] + bhhs[1][gj0+1]);
      float n1 = tanhff(xn1 + bihs[2][gj0+1] + r1*(gh[2][gb][gj0+1] + bhhs[2][gj0+1]));
      hv1 = (1.f - z1)*n1 + z1*hp1;
      hp0 = hv0; hp1 = hv1;

      // publish h_new pair to next image (agent -> LLC)
      u32* img2 = (u32*)(himg + ((size_t)dir*2 + ((t + 1) & 1)) * 32 * 512);
      pv = (u32)f2bf(hv0) | ((u32)f2bf(hv1) << 16);
      __hip_atomic_store(img2 + gb*256 + jb*16 + (tid & 15), pv,
                         __ATOMIC_RELAXED, __HIP_MEMORY_SCOPE_AGENT);
    }

    // --- per-wave drain (parallel) -> LDS counter -> 8th wave releases WG flag ---
    asm volatile("s_waitcnt vmcnt(0)" ::: "memory");
    if (lane == 0) {
      u32 old = atomicAdd(&lctr, 1u);
      if (old == (u32)(t*8 + 7))
        __hip_atomic_store(myflag, (u32)(t + 1), __ATOMIC_RELAXED, __HIP_MEMORY_SCOPE_AGENT);
    }

    // --- out store after flag (drains during next poll window) ---
    {
      size_t oi = (size_t)(gb*TT + tt)*1024 + dir*512 + jb*CPW + gj0;
      if (outf32) {
        f32x2 ov; ov.x = hv0; ov.y = hv1;
        __builtin_nontemporal_store(ov, (f32x2*)((float*)out + oi));
      } else {
        __builtin_nontemporal_store(pv, (u32*)((u16*)out + oi));
      }
    }
  }
}

// ---------------- host ----------------
extern "C" void kernel_launch(void* const* d_in, const int* in_sizes, int n_in,
                              void* d_out, int out_size, void* d_ws, size_t ws_size,
                              hipStream_t stream) {
  (void)in_sizes; (void)n_in; (void)out_size;
  const float* x    = (const float*)d_in[0];
  const float* wih0 = (const float*)d_in[1];
  const float* whh0 = (const float*)d_in[2];
  const float* bih0 = (const float*)d_in[3];
  const float* bhh0 = (const float*)d_in[4];
  const float* wih1 = (const float*)d_in[5];
  const float* whh1 = (const float*)d_in[6];
  const float* bih1 = (const float*)d_in[7];
  const float* bhh1 = (const float*)d_in[8];

  char* ws = (char*)d_ws;
  size_t off = 0;
  auto alloc = [&](size_t bytes) { size_t o = off; off += (bytes + 255) & ~(size_t)255; return o; };
  size_t off_xb   = alloc((size_t)MM * 512 * 2);       // x bf16
  size_t off_wih0 = alloc((size_t)3072 * 512 * 2);
  size_t off_wih1 = alloc((size_t)3072 * 1024 * 2);
  size_t off_whh0 = alloc((size_t)3072 * 512 * 2);
  size_t off_whh1 = alloc((size_t)3072 * 512 * 2);
  size_t off_h0   = alloc((size_t)MM * 1024 * 2);      // layer-0 output bf16
  size_t off_sync = alloc(131072 + 4096);              // h images (128KB) + flags
  size_t off_gx   = off;                               // gx last
  int gxf32 = (ws_size >= off_gx + (size_t)MM * NG * 4) ? 1 : 0;

  u16* xb    = (u16*)(ws + off_xb);
  u16* wih0b = (u16*)(ws + off_wih0);
  u16* wih1b = (u16*)(ws + off_wih1);
  u16* whh0b = (u16*)(ws + off_whh0);
  u16* whh1b = (u16*)(ws + off_whh1);
  u16* h0b   = (u16*)(ws + off_h0);
  u16* himg  = (u16*)(ws + off_sync);
  u32* flags = (u32*)(ws + off_sync + 131072);
  char* gx   = ws + off_gx;

  cvt_bf16<<<4096, 256, 0, stream>>>(x,    xb,    MM*512/8);
  cvt_bf16<<<768,  256, 0, stream>>>(wih0, wih0b, 3072*512/8);
  cvt_bf16<<<1536, 256, 0, stream>>>(wih1, wih1b, 3072*1024/8);
  cvt_bf16<<<768,  256, 0, stream>>>(whh0, whh0b, 3072*512/8);
  cvt_bf16<<<768,  256, 0, stream>>>(whh1, whh1b, 3072*512/8);

  dim3 ggrid(NG/128, MM/128);   // (24, 128)

  // layer 0
  gemm_gx<<<ggrid, 256, 0, stream>>>(xb, wih0b, gx, 512, gxf32);
  (void)hipMemsetAsync(ws + off_sync, 0, 131072 + 4096, stream);
  bigru_rec<<<32, 512, 0, stream>>>(gx, whh0b, bih0, bhh0, (char*)h0b, himg, flags, gxf32, 0);

  // layer 1
  gemm_gx<<<ggrid, 256, 0, stream>>>(h0b, wih1b, gx, 1024, gxf32);
  (void)hipMemsetAsync(ws + off_sync, 0, 131072 + 4096, stream);
  bigru_rec<<<32, 512, 0, stream>>>(gx, whh1b, bih1, bhh1, (char*)d_out, himg, flags, gxf32, 1);
}

// Round 11
// 5606.717 us; speedup vs baseline: 2.3551x; 2.3551x over previous
//
#include <hip/hip_runtime.h>
#include <hip/hip_bf16.h>
#include <stdint.h>

#define TT 512
#define HD 512
#define BB 32
#define MM (BB*TT)     // 16384 rows (b*T+t)
#define NG 3072        // 2 dirs * 3 gates * 512
#define WGD 8          // workgroups per direction
#define CPW 64         // h columns per workgroup

typedef short short8 __attribute__((ext_vector_type(8)));
typedef float f32x4 __attribute__((ext_vector_type(4)));
typedef float f32x2 __attribute__((ext_vector_type(2)));
typedef unsigned short u16;
typedef unsigned int u32;
typedef unsigned long long u64;

__device__ __forceinline__ u16 f2bf(float f) {
  __hip_bfloat16 h = __float2bfloat16(f);
  union { __hip_bfloat16 h; u16 u; } c; c.h = h; return c.u;
}
__device__ __forceinline__ float bf2f(u16 u) {
  union { u32 i; float f; } c; c.i = ((u32)u) << 16; return c.f;
}
__device__ __forceinline__ float sigmf(float x) {
  return 1.0f / (1.0f + __expf(-x));
}
__device__ __forceinline__ float tanhff(float x) {
  float a = __expf(2.0f * x);          // inf -> 1, 0 -> -1 : graceful
  return 1.0f - 2.0f / (a + 1.0f);
}

// ---------------- f32 -> bf16 convert ----------------
__global__ __launch_bounds__(256) void cvt_bf16(const float* __restrict__ in,
                                                u16* __restrict__ out, int n8) {
  int i = blockIdx.x * 256 + threadIdx.x;
  if (i >= n8) return;
  const float4* p = (const float4*)in;
  float4 a = p[2*i], b = p[2*i+1];
  union { short8 v; u16 u[8]; } o;
  o.u[0]=f2bf(a.x); o.u[1]=f2bf(a.y); o.u[2]=f2bf(a.z); o.u[3]=f2bf(a.w);
  o.u[4]=f2bf(b.x); o.u[5]=f2bf(b.y); o.u[6]=f2bf(b.z); o.u[7]=f2bf(b.w);
  ((short8*)out)[i] = o.v;
}

// ---------------- gx GEMM (unchanged) ----------------
__global__ __launch_bounds__(256) void gemm_gx(const u16* __restrict__ A,
                                               const u16* __restrict__ Bw,
                                               char* __restrict__ gxout,
                                               int K, int gxf32) {
  __shared__ __align__(16) u16 lA[128*32];
  __shared__ __align__(16) u16 lB[128*32];
  const int tid = threadIdx.x;
  const int lane = tid & 63;
  const int wid = tid >> 6;
  const int wr = wid >> 1, wc = wid & 1;
  const int bm = blockIdx.y * 128, bn = blockIdx.x * 128;
  const int col = lane & 15, kg = lane >> 4;

  f32x4 acc[4][4];
#pragma unroll
  for (int m = 0; m < 4; ++m)
#pragma unroll
    for (int n = 0; n < 4; ++n) acc[m][n] = (f32x4){0.f,0.f,0.f,0.f};

  const int nkt = K >> 5;
  for (int kt = 0; kt < nkt; ++kt) {
    short8 ra[2], rb[2];
    const int kb = kt * 32;
#pragma unroll
    for (int p = 0; p < 2; ++p) {
      int id = p*256 + tid;
      int row = id >> 2, c = id & 3;
      ra[p] = *(const short8*)(A  + (size_t)(bm+row)*K + kb + c*8);
      rb[p] = *(const short8*)(Bw + (size_t)(bn+row)*K + kb + c*8);
    }
    __syncthreads();
#pragma unroll
    for (int p = 0; p < 2; ++p) {
      int id = p*256 + tid;
      int row = id >> 2, c = id & 3;
      int off = row*64 + ((c ^ ((row>>1)&3))*16);
      *(short8*)((char*)lA + off) = ra[p];
      *(short8*)((char*)lB + off) = rb[p];
    }
    __syncthreads();
    short8 af[4], bf[4];
#pragma unroll
    for (int m = 0; m < 4; ++m) {
      int row = wr*64 + m*16 + col;
      af[m] = *(short8*)((char*)lA + row*64 + ((kg ^ ((row>>1)&3))*16));
    }
#pragma unroll
    for (int n = 0; n < 4; ++n) {
      int row = wc*64 + n*16 + col;
      bf[n] = *(short8*)((char*)lB + row*64 + ((kg ^ ((row>>1)&3))*16));
    }
#pragma unroll
    for (int m = 0; m < 4; ++m)
#pragma unroll
      for (int n = 0; n < 4; ++n)
        acc[m][n] = __builtin_amdgcn_mfma_f32_16x16x32_bf16(af[m], bf[n], acc[m][n], 0,0,0);
  }
#pragma unroll
  for (int m = 0; m < 4; ++m)
#pragma unroll
    for (int n = 0; n < 4; ++n)
#pragma unroll
      for (int r = 0; r < 4; ++r) {
        int rowg = bm + wr*64 + m*16 + kg*4 + r;
        int colg = bn + wc*64 + n*16 + col;
        float v = acc[m][n][r];
        if (gxf32) ((float*)gxout)[(size_t)rowg*NG + colg] = v;
        else       ((u16*)gxout)[(size_t)rowg*NG + colg] = f2bf(v);
      }
}

// ---------------- persistent BiGRU recurrence (8 producers/dir) ----------------
// grid = 16 WGs (512 thr, 8 waves): dir = wg>>3, jb = wg&7 -> cols [jb*64,+64).
// Wave w polls ONLY producer w's flag (one flag/WG; 16 waves/line vs R9's 192)
// then reads its 4KB slice (8 u64/lane) -> swizzled LDS. MFMA waves 0..5 own
// 2 (gate,colblock) pairs each (bfrag 128 VGPR; shared A-fragments). gx is
// per-thread direct register loads (no LDS staging). gh exchange via LDS,
// gates 4 cols/thread, publish one u64 agent store, parallel drain -> WG flag.
__global__ __launch_bounds__(512, 2) void bigru_rec(const char* __restrict__ gx,
                                                    const u16* __restrict__ whhb,
                                                    const float* __restrict__ b_ih,
                                                    const float* __restrict__ b_hh,
                                                    char* __restrict__ out,
                                                    u16* __restrict__ himg,   // [2][2][32][512]
                                                    u32* __restrict__ flags,  // [2][8] stride 16 dwords
                                                    int gxf32, int outf32) {
  const int wg = blockIdx.x;
  const int dir = wg >> 3;
  const int jb = wg & 7;
  const int tid = threadIdx.x;
  const int lane = tid & 63;
  const int wv = tid >> 6;
  const int col = lane & 15, kg = lane >> 4;

  __shared__ __align__(16) u16 hstage[32*512];     // 32 KB, swizzled
  __shared__ float gh[3][32][68];                  // 26 KB, padded (stride 272B)
  __shared__ float bihs[3][64], bhhs[3][64];
  __shared__ u32 lctr;

  // --- one-time: w_hh B-fragments (waves 0..5, pairs 2w, 2w+1 of 12) ---
  // pair pi: gate g = pi>>2, colblock cb = pi&3 (16 cols each)
  short8 bfr0[16], bfr1[16];
  if (wv < 6) {
    const int pi0 = 2*wv, pi1 = 2*wv + 1;
    const u16* w0 = whhb + (size_t)(dir*1536 + (pi0>>2)*512 + jb*CPW + (pi0&3)*16 + col) * 512;
    const u16* w1 = whhb + (size_t)(dir*1536 + (pi1>>2)*512 + jb*CPW + (pi1&3)*16 + col) * 512;
#pragma unroll
    for (int kc = 0; kc < 16; ++kc) {
      bfr0[kc] = *(const short8*)(w0 + kc*32 + kg*8);
      bfr1[kc] = *(const short8*)(w1 + kc*32 + kg*8);
    }
  }
  if (tid < 192) {
    int g = tid >> 6, j = tid & 63;
    bihs[g][j] = b_ih[dir*1536 + g*512 + jb*CPW + j];
    bhhs[g][j] = b_hh[dir*1536 + g*512 + jb*CPW + j];
  }
  if (tid == 0) lctr = 0;
  __syncthreads();

  // gate ownership: thread -> (b = tid>>4, cols j0..j0+3)
  const int gb = tid >> 4, gj0 = (tid & 15) * 4;
  float hp[4] = {0.f, 0.f, 0.f, 0.f};

  u32* dirflags = flags + (size_t)dir * WGD * 16;
  u32* myflag = dirflags + (size_t)jb * 16;

  // slice read: wave w owns producer w; lane -> row=lane>>1, half=lane&1 (8 u64)
  const int srow = lane >> 1, shalf = lane & 1;
  const u32* fpw = dirflags + (size_t)wv * 16;

  for (int t = 0; t < TT; ++t) {
    const int tt = dir ? (TT - 1 - t) : t;
    const int par = t & 1;

    // --- gx[tt] -> registers (issued early; retire under poll) ---
    float4 xr4, xz4, xn4; u64 xrB=0, xzB=0, xnB=0;
    if (gxf32) {
      const float* gp = (const float*)gx + (size_t)(gb*TT+tt)*NG + dir*1536 + jb*CPW + gj0;
      xr4 = *(const float4*)(gp);
      xz4 = *(const float4*)(gp + 512);
      xn4 = *(const float4*)(gp + 1024);
    } else {
      const u16* gp = (const u16*)gx + (size_t)(gb*TT+tt)*NG + dir*1536 + jb*CPW + gj0;
      xrB = *(const u64*)(gp);
      xzB = *(const u64*)(gp + 512);
      xnB = *(const u64*)(gp + 1024);
    }

    // --- poll own producer's flag, then read its 4KB slice ---
    if (t > 0) {
      const u32 need = (u32)t;
      int it = 0;
      while (__hip_atomic_load(fpw, __ATOMIC_RELAXED, __HIP_MEMORY_SCOPE_AGENT) < need && it++ < (1<<24)) {}
    }
    __builtin_amdgcn_sched_barrier(0);
    asm volatile("" ::: "memory");   // pin slice loads AFTER the poll

    const u64* imgr = (const u64*)(himg + ((size_t)dir*2 + par) * 32 * 512);
    u64 v[8];
#pragma unroll
    for (int j = 0; j < 8; ++j)
      v[j] = __hip_atomic_load(imgr + srow*128 + wv*16 + shalf*8 + j,
                               __ATOMIC_RELAXED, __HIP_MEMORY_SCOPE_AGENT);
#pragma unroll
    for (int j = 0; j < 8; ++j) {
      int d2 = wv*16 + shalf*8 + j; int c = d2 >> 1;
      *(u64*)((char*)hstage + srow*1024 + (((c ^ (srow & 7)) << 4) | ((d2 & 1) << 3))) = v[j];
    }
    __syncthreads();   // (B) full image staged

    // --- MFMA: waves 0..5, 2 pairs x 2 M-tiles x 16 kc (shared A-fragments) ---
    if (wv < 6) {
      f32x4 a00 = (f32x4){0.f,0.f,0.f,0.f}, a01 = a00, a10 = a00, a11 = a00;
#pragma unroll
      for (int kc = 0; kc < 16; ++kc) {
        int c = kc*4 + kg;
        short8 h0 = *(short8*)((char*)hstage + col*1024      + ((c ^ (col & 7)) << 4));
        short8 h1 = *(short8*)((char*)hstage + (16+col)*1024 + ((c ^ (col & 7)) << 4));
        a00 = __builtin_amdgcn_mfma_f32_16x16x32_bf16(h0, bfr0[kc], a00, 0,0,0);
        a01 = __builtin_amdgcn_mfma_f32_16x16x32_bf16(h1, bfr0[kc], a01, 0,0,0);
        a10 = __builtin_amdgcn_mfma_f32_16x16x32_bf16(h0, bfr1[kc], a10, 0,0,0);
        a11 = __builtin_amdgcn_mfma_f32_16x16x32_bf16(h1, bfr1[kc], a11, 0,0,0);
      }
      const int pi0 = 2*wv, pi1 = 2*wv + 1;
      const int g0 = pi0 >> 2, cb0 = pi0 & 3;
      const int g1 = pi1 >> 2, cb1 = pi1 & 3;
#pragma unroll
      for (int r = 0; r < 4; ++r) {
        gh[g0][kg*4 + r][cb0*16 + col]      = a00[r];
        gh[g0][16 + kg*4 + r][cb0*16 + col] = a01[r];
        gh[g1][kg*4 + r][cb1*16 + col]      = a10[r];
        gh[g1][16 + kg*4 + r][cb1*16 + col] = a11[r];
      }
    }
    __syncthreads();   // (C) gh ready

    // --- gates: thread -> (b=gb, cols gj0..gj0+3) ---
    float hv[4];
    {
      float xr[4], xz[4], xn[4];
      if (gxf32) {
        xr[0]=xr4.x; xr[1]=xr4.y; xr[2]=xr4.z; xr[3]=xr4.w;
        xz[0]=xz4.x; xz[1]=xz4.y; xz[2]=xz4.z; xz[3]=xz4.w;
        xn[0]=xn4.x; xn[1]=xn4.y; xn[2]=xn4.z; xn[3]=xn4.w;
      } else {
#pragma unroll
        for (int jj = 0; jj < 4; ++jj) {
          xr[jj] = bf2f((u16)(xrB >> (16*jj)));
          xz[jj] = bf2f((u16)(xzB >> (16*jj)));
          xn[jj] = bf2f((u16)(xnB >> (16*jj)));
        }
      }
#pragma unroll
      for (int jj = 0; jj < 4; ++jj) {
        int j = gj0 + jj;
        float rg = sigmf(xr[jj] + bihs[0][j] + gh[0][gb][j] + bhhs[0][j]);
        float zg = sigmf(xz[jj] + bihs[1][j] + gh[1][gb][j] + bhhs[1][j]);
        float ng = tanhff(xn[jj] + bihs[2][j] + rg*(gh[2][gb][j] + bhhs[2][j]));
        hv[jj] = (1.f - zg)*ng + zg*hp[jj];
        hp[jj] = hv[jj];
      }
    }

    // --- publish 4 bf16 as one u64 (agent -> LLC) ---
    u64 pv = (u64)f2bf(hv[0]) | ((u64)f2bf(hv[1]) << 16)
           | ((u64)f2bf(hv[2]) << 32) | ((u64)f2bf(hv[3]) << 48);
    {
      u64* img2 = (u64*)(himg + ((size_t)dir*2 + ((t + 1) & 1)) * 32 * 512);
      __hip_atomic_store(img2 + gb*128 + jb*16 + (gj0 >> 2), pv,
                         __ATOMIC_RELAXED, __HIP_MEMORY_SCOPE_AGENT);
    }

    // --- per-wave drain (parallel) -> LDS counter -> 8th wave releases WG flag ---
    asm volatile("s_waitcnt vmcnt(0)" ::: "memory");
    if (lane == 0) {
      u32 old = atomicAdd(&lctr, 1u);
      if (old == (u32)(t*8 + 7))
        __hip_atomic_store(myflag, (u32)(t + 1), __ATOMIC_RELAXED, __HIP_MEMORY_SCOPE_AGENT);
    }

    // --- out store after flag (drains during next poll window) ---
    {
      size_t oi = (size_t)(gb*TT + tt)*1024 + dir*512 + jb*CPW + gj0;
      if (outf32) {
        f32x4 ov; ov[0]=hv[0]; ov[1]=hv[1]; ov[2]=hv[2]; ov[3]=hv[3];
        __builtin_nontemporal_store(ov, (f32x4*)((float*)out + oi));
      } else {
        __builtin_nontemporal_store(pv, (u64*)((u16*)out + oi));
      }
    }
  }
}

// ---------------- host ----------------
extern "C" void kernel_launch(void* const* d_in, const int* in_sizes, int n_in,
                              void* d_out, int out_size, void* d_ws, size_t ws_size,
                              hipStream_t stream) {
  (void)in_sizes; (void)n_in; (void)out_size;
  const float* x    = (const float*)d_in[0];
  const float* wih0 = (const float*)d_in[1];
  const float* whh0 = (const float*)d_in[2];
  const float* bih0 = (const float*)d_in[3];
  const float* bhh0 = (const float*)d_in[4];
  const float* wih1 = (const float*)d_in[5];
  const float* whh1 = (const float*)d_in[6];
  const float* bih1 = (const float*)d_in[7];
  const float* bhh1 = (const float*)d_in[8];

  char* ws = (char*)d_ws;
  size_t off = 0;
  auto alloc = [&](size_t bytes) { size_t o = off; off += (bytes + 255) & ~(size_t)255; return o; };
  size_t off_xb   = alloc((size_t)MM * 512 * 2);       // x bf16
  size_t off_wih0 = alloc((size_t)3072 * 512 * 2);
  size_t off_wih1 = alloc((size_t)3072 * 1024 * 2);
  size_t off_whh0 = alloc((size_t)3072 * 512 * 2);
  size_t off_whh1 = alloc((size_t)3072 * 512 * 2);
  size_t off_h0   = alloc((size_t)MM * 1024 * 2);      // layer-0 output bf16
  size_t off_sync = alloc(131072 + 4096);              // h images (128KB) + flags
  size_t off_gx   = off;                               // gx last
  int gxf32 = (ws_size >= off_gx + (size_t)MM * NG * 4) ? 1 : 0;

  u16* xb    = (u16*)(ws + off_xb);
  u16* wih0b = (u16*)(ws + off_wih0);
  u16* wih1b = (u16*)(ws + off_wih1);
  u16* whh0b = (u16*)(ws + off_whh0);
  u16* whh1b = (u16*)(ws + off_whh1);
  u16* h0b   = (u16*)(ws + off_h0);
  u16* himg  = (u16*)(ws + off_sync);
  u32* flags = (u32*)(ws + off_sync + 131072);
  char* gx   = ws + off_gx;

  cvt_bf16<<<4096, 256, 0, stream>>>(x,    xb,    MM*512/8);
  cvt_bf16<<<768,  256, 0, stream>>>(wih0, wih0b, 3072*512/8);
  cvt_bf16<<<1536, 256, 0, stream>>>(wih1, wih1b, 3072*1024/8);
  cvt_bf16<<<768,  256, 0, stream>>>(whh0, whh0b, 3072*512/8);
  cvt_bf16<<<768,  256, 0, stream>>>(whh1, whh1b, 3072*512/8);

  dim3 ggrid(NG/128, MM/128);   // (24, 128)

  // layer 0
  gemm_gx<<<ggrid, 256, 0, stream>>>(xb, wih0b, gx, 512, gxf32);
  (void)hipMemsetAsync(ws + off_sync, 0, 131072 + 4096, stream);
  bigru_rec<<<16, 512, 0, stream>>>(gx, whh0b, bih0, bhh0, (char*)h0b, himg, flags, gxf32, 0);

  // layer 1
  gemm_gx<<<ggrid, 256, 0, stream>>>(h0b, wih1b, gx, 1024, gxf32);
  (void)hipMemsetAsync(ws + off_sync, 0, 131072 + 4096, stream);
  bigru_rec<<<16, 512, 0, stream>>>(gx, whh1b, bih1, bhh1, (char*)d_out, himg, flags, gxf32, 1);
}